// Round 1
// 12899.797 us; speedup vs baseline: 2.7908x; 2.7908x over previous
//
#include <hip/hip_runtime.h>
#include <math.h>

// Problem constants (Qwen3-MoE tiny config)
#define BB    2
#define SS    1024
#define TT    2048          // B*S tokens
#define DD    1024          // model dim
#define HH    16            // q heads
#define KVH   4             // kv heads
#define HDIM  64            // head dim
#define LL    4             // layers
#define EE    8             // experts
#define FF    1024          // ffn dim
#define VV    32000         // vocab
#define EPSF  1e-6f
#define NSLOT 4096          // TT * TOPK slots

// ---------------------------------------------------------------------------
// embedding gather
__global__ void k_embed(const int* __restrict__ tok, const float* __restrict__ emb,
                        float* __restrict__ x) {
    int t = blockIdx.x;
    int id = tok[t];
    const float* src = emb + (size_t)id * DD;
    float* dst = x + (size_t)t * DD;
    for (int i = threadIdx.x; i < DD; i += blockDim.x) dst[i] = src[i];
}

// ---------------------------------------------------------------------------
// RMSNorm over D=1024, one block per row
__global__ void k_rmsnorm(const float* __restrict__ x, const float* __restrict__ w,
                          float* __restrict__ out) {
    int t = blockIdx.x;
    const float* row = x + (size_t)t * DD;
    float ss = 0.f;
    for (int i = threadIdx.x; i < DD; i += blockDim.x) { float v = row[i]; ss += v * v; }
    __shared__ float red[4];
    for (int o = 32; o > 0; o >>= 1) ss += __shfl_down(ss, o, 64);
    int lane = threadIdx.x & 63, wid = threadIdx.x >> 6;
    if (lane == 0) red[wid] = ss;
    __syncthreads();
    float tot = red[0] + red[1] + red[2] + red[3];
    float r = rsqrtf(tot / (float)DD + EPSF);
    float* o_ = out + (size_t)t * DD;
    for (int i = threadIdx.x; i < DD; i += blockDim.x) o_[i] = row[i] * r * w[i];
}

// ---------------------------------------------------------------------------
// 64x64 fp32 GEMM body. LDS stored [k][m] / [k][n] so the inner loop uses
// ds_read_b128 (2 per 16 FMAs instead of 8 scalar ds_read_b32).
// Thread (tx,ty) owns rows row0+ty*4..+3, cols col0+tx*4..+3 (float4 stores).
__device__ __forceinline__ void gemm64_body(const float* __restrict__ A,
        const float* __restrict__ B, float* __restrict__ C,
        int M, int N, int K, int accum) {
    __shared__ __align__(16) float As[16][68];
    __shared__ __align__(16) float Bs[16][68];
    const int tx = threadIdx.x, ty = threadIdx.y;
    const int tid = ty * 16 + tx;
    const int row0 = blockIdx.y << 6, col0 = blockIdx.x << 6;
    const int am = tid >> 2, ak = (tid & 3) << 2;    // A: 64 rows x 16 k
    const int bk = tid >> 4, bn = (tid & 15) << 2;   // B: 16 k x 64 cols
    float acc[4][4] = {};
    for (int k0 = 0; k0 < K; k0 += 16) {
        float4 av = make_float4(0.f, 0.f, 0.f, 0.f);
        const int gr = row0 + am;
        if (gr < M) av = *(const float4*)(A + (size_t)gr * K + (k0 + ak));
        As[ak + 0][am] = av.x; As[ak + 1][am] = av.y;
        As[ak + 2][am] = av.z; As[ak + 3][am] = av.w;
        float4 bv = make_float4(0.f, 0.f, 0.f, 0.f);
        const int gc = col0 + bn;
        const float* bp = B + (size_t)(k0 + bk) * N + gc;
        if (gc + 3 < N) bv = *(const float4*)bp;
        else if (gc < N) {
            bv.x = bp[0];
            if (gc + 1 < N) bv.y = bp[1];
            if (gc + 2 < N) bv.z = bp[2];
        }
        *(float4*)&Bs[bk][bn] = bv;
        __syncthreads();
#pragma unroll
        for (int kk = 0; kk < 16; kk++) {
            const float4 a4 = *(const float4*)&As[kk][ty << 2];
            const float4 b4 = *(const float4*)&Bs[kk][tx << 2];
            const float ar[4] = {a4.x, a4.y, a4.z, a4.w};
            const float br[4] = {b4.x, b4.y, b4.z, b4.w};
#pragma unroll
            for (int i = 0; i < 4; i++)
#pragma unroll
                for (int j = 0; j < 4; j++)
                    acc[i][j] = fmaf(ar[i], br[j], acc[i][j]);
        }
        __syncthreads();
    }
#pragma unroll
    for (int i = 0; i < 4; i++) {
        const int gr = row0 + (ty << 2) + i;
        if (gr >= M) continue;
        const int gc = col0 + (tx << 2);
        float* cp = C + (size_t)gr * N + gc;
        if (gc + 3 < N) {
            float4 v = make_float4(acc[i][0], acc[i][1], acc[i][2], acc[i][3]);
            if (accum) {
                const float4 o = *(const float4*)cp;
                v.x += o.x; v.y += o.y; v.z += o.z; v.w += o.w;
            }
            *(float4*)cp = v;
        } else {
#pragma unroll
            for (int j = 0; j < 4; j++)
                if (gc + j < N) {
                    float v = acc[i][j];
                    if (accum) v += cp[j];
                    cp[j] = v;
                }
        }
    }
}

__global__ __launch_bounds__(256) void k_gemm_nn(const float* __restrict__ A,
        const float* __restrict__ B, float* __restrict__ C, int M, int N, int K,
        int accum) {
    gemm64_body(A, B, C, M, N, K, accum);
}

// q/k/v fused into one launch: blockIdx.z selects {wq,wk,wv}
__global__ __launch_bounds__(256) void k_gemm_qkv(const float* __restrict__ h,
        const float* __restrict__ wq, const float* __restrict__ wk,
        const float* __restrict__ wv, float* __restrict__ qb,
        float* __restrict__ kb, float* __restrict__ vb) {
    const int z = blockIdx.z;
    const int N = (z == 0) ? (HH * HDIM) : (KVH * HDIM);
    if ((int)(blockIdx.x << 6) >= N) return;
    const float* B = (z == 0) ? wq : (z == 1 ? wk : wv);
    float* C = (z == 0) ? qb : (z == 1 ? kb : vb);
    gemm64_body(h, B, C, TT, N, DD, 0);
}

// ---------------------------------------------------------------------------
// GEMM-NT for the LM head: C[M,N] = A[M,K] @ B[N,K]^T (K contiguous in both)
__global__ __launch_bounds__(256) void k_gemm_nt(const float* __restrict__ A,
        const float* __restrict__ B, float* __restrict__ C, int M, int N, int K) {
    __shared__ __align__(16) float As[16][68];
    __shared__ __align__(16) float Bs[16][68];
    const int tx = threadIdx.x, ty = threadIdx.y;
    const int tid = ty * 16 + tx;
    const int row0 = blockIdx.y << 6, col0 = blockIdx.x << 6;
    const int am = tid >> 2, ak = (tid & 3) << 2;
    float acc[4][4] = {};
    for (int k0 = 0; k0 < K; k0 += 16) {
        float4 av = make_float4(0.f, 0.f, 0.f, 0.f);
        const int gr = row0 + am;
        if (gr < M) av = *(const float4*)(A + (size_t)gr * K + (k0 + ak));
        As[ak + 0][am] = av.x; As[ak + 1][am] = av.y;
        As[ak + 2][am] = av.z; As[ak + 3][am] = av.w;
        float4 bv = make_float4(0.f, 0.f, 0.f, 0.f);
        const int gn = col0 + am;
        if (gn < N) bv = *(const float4*)(B + (size_t)gn * K + (k0 + ak));
        Bs[ak + 0][am] = bv.x; Bs[ak + 1][am] = bv.y;
        Bs[ak + 2][am] = bv.z; Bs[ak + 3][am] = bv.w;
        __syncthreads();
#pragma unroll
        for (int kk = 0; kk < 16; kk++) {
            const float4 a4 = *(const float4*)&As[kk][ty << 2];
            const float4 b4 = *(const float4*)&Bs[kk][tx << 2];
            const float ar[4] = {a4.x, a4.y, a4.z, a4.w};
            const float br[4] = {b4.x, b4.y, b4.z, b4.w};
#pragma unroll
            for (int i = 0; i < 4; i++)
#pragma unroll
                for (int j = 0; j < 4; j++)
                    acc[i][j] = fmaf(ar[i], br[j], acc[i][j]);
        }
        __syncthreads();
    }
#pragma unroll
    for (int i = 0; i < 4; i++) {
        const int gr = row0 + (ty << 2) + i;
        if (gr >= M) continue;
        const int gc = col0 + (tx << 2);
        float* cp = C + (size_t)gr * N + gc;
        if (gc + 3 < N) {
            *(float4*)cp = make_float4(acc[i][0], acc[i][1], acc[i][2], acc[i][3]);
        } else {
#pragma unroll
            for (int j = 0; j < 4; j++)
                if (gc + j < N) cp[j] = acc[i][j];
        }
    }
}

// ---------------------------------------------------------------------------
// per-head RMSNorm (over 64 dims) + RoPE. One 64-lane wave per (token, head).
__global__ void k_qknorm_rope(float* __restrict__ q, const float* __restrict__ nw,
                              const int* __restrict__ pos_ids, int nheads) {
    int g = blockIdx.x * 4 + (threadIdx.x >> 6);
    int lane = threadIdx.x & 63;
    int t = g / nheads, head = g % nheads;
    size_t base = (size_t)t * nheads * HDIM + (size_t)head * HDIM;
    float v = q[base + lane];
    float ss = v * v;
    for (int o = 32; o > 0; o >>= 1) ss += __shfl_xor(ss, o, 64);
    float r = rsqrtf(ss / (float)HDIM + EPSF);
    v = v * r * nw[lane];
    int pos = pos_ids[t];
    int i = lane & 31;
    float freq = powf(1000000.0f, -(float)i / 32.0f);
    float ang = (float)pos * freq;
    float c = cosf(ang), s = sinf(ang);
    float partner = __shfl_xor(v, 32, 64);
    float outv = (lane < 32) ? (v * c - partner * s) : (v * c + partner * s);
    q[base + lane] = outv;
}

// ---------------------------------------------------------------------------
// causal attention, one block per (query position, b*H+h)
__global__ void k_attn(const float* __restrict__ q, const float* __restrict__ k,
                       const float* __restrict__ v, float* __restrict__ o) {
    int s = blockIdx.x;
    int bh = blockIdx.y;
    int b = bh / HH, h = bh % HH;
    int kvh = h >> 2;
    int t = b * SS + s;
    __shared__ float qs[HDIM];
    __shared__ float sc[SS];
    __shared__ float redm[4];
    __shared__ float reds[4];
    __shared__ float part[4][HDIM];
    int tid = threadIdx.x;
    int lane = tid & 63, wid = tid >> 6;
    if (tid < HDIM) qs[tid] = q[(size_t)t * HH * HDIM + h * HDIM + tid];
    __syncthreads();
    const float scale = 0.125f;
    for (int j = tid; j <= s; j += 256) {
        const float* kr = k + ((size_t)(b * SS + j) * KVH + kvh) * HDIM;
        float d = 0.f;
#pragma unroll
        for (int x = 0; x < HDIM; x++) d = fmaf(qs[x], kr[x], d);
        sc[j] = d * scale;
    }
    __syncthreads();
    float m = -1e30f;
    for (int j = tid; j <= s; j += 256) m = fmaxf(m, sc[j]);
    for (int o2 = 32; o2 > 0; o2 >>= 1) m = fmaxf(m, __shfl_xor(m, o2, 64));
    if (lane == 0) redm[wid] = m;
    __syncthreads();
    m = fmaxf(fmaxf(redm[0], redm[1]), fmaxf(redm[2], redm[3]));
    float sum = 0.f;
    for (int j = tid; j <= s; j += 256) { float e = expf(sc[j] - m); sc[j] = e; sum += e; }
    for (int o2 = 32; o2 > 0; o2 >>= 1) sum += __shfl_xor(sum, o2, 64);
    if (lane == 0) reds[wid] = sum;
    __syncthreads();
    sum = reds[0] + reds[1] + reds[2] + reds[3];
    float inv = 1.f / sum;
    float accd = 0.f;
    for (int j = wid; j <= s; j += 4)
        accd = fmaf(sc[j], v[((size_t)(b * SS + j) * KVH + kvh) * HDIM + lane], accd);
    part[wid][lane] = accd;
    __syncthreads();
    if (wid == 0) {
        float r2 = (part[0][lane] + part[1][lane] + part[2][lane] + part[3][lane]) * inv;
        o[(size_t)t * HH * HDIM + h * HDIM + lane] = r2;
    }
}

// ---------------------------------------------------------------------------
// MoE routing: top-2 of 8, bucket tokens per expert
__global__ void k_zero_counts(int* __restrict__ counts) {
    if (threadIdx.x < EE) counts[threadIdx.x] = 0;
}

__global__ void k_router_build(const float* __restrict__ rl, int* __restrict__ counts,
                               int* __restrict__ tmp_tok, float* __restrict__ tmp_gv) {
    int t = blockIdx.x * 256 + threadIdx.x;
    if (t >= TT) return;
    const float* lg = rl + (size_t)t * EE;
    int i0 = 0; float l0 = lg[0];
    for (int e = 1; e < EE; e++) { float v = lg[e]; if (v > l0) { l0 = v; i0 = e; } }
    int i1 = -1; float l1 = -1e30f;
    for (int e = 0; e < EE; e++) {
        if (e == i0) continue;
        float v = lg[e];
        if (i1 < 0 || v > l1) { l1 = v; i1 = e; }
    }
    // normalized top-2 softmax weights (denominator cancels)
    float d = expf(l1 - l0);
    float w0 = 1.f / (1.f + d);
    float w1 = d / (1.f + d);
    int p = atomicAdd(&counts[i0], 1);
    tmp_tok[i0 * TT + p] = t; tmp_gv[i0 * TT + p] = w0;
    p = atomicAdd(&counts[i1], 1);
    tmp_tok[i1 * TT + p] = t; tmp_gv[i1 * TT + p] = w1;
}

// compact per-expert lists into contiguous slot space (total slots = NSLOT)
__global__ void k_compact(const int* __restrict__ counts, int* __restrict__ offs,
                          const int* __restrict__ tmp_tok, const float* __restrict__ tmp_gv,
                          int* __restrict__ tok, float* __restrict__ gv) {
    __shared__ int so[EE];
    int tid = threadIdx.x;
    if (tid == 0) {
        int r = 0;
        for (int e = 0; e < EE; e++) { so[e] = r; offs[e] = r; r += counts[e]; }
    }
    __syncthreads();
    for (int e = 0; e < EE; e++) {
        int c = counts[e], o = so[e];
        for (int i = tid; i < c; i += 256) {
            tok[o + i] = tmp_tok[e * TT + i];
            gv[o + i]  = tmp_gv[e * TT + i];
        }
    }
}

// ---------------------------------------------------------------------------
// grouped gather gate+up GEMM with fused silu: t3[slot] = silu(h@gw) * (h@uw)
// grid (FF/64, TT/64, EE); blocks past the expert's token count exit early.
__global__ __launch_bounds__(256) void k_moe_gateup(const float* __restrict__ h,
        const float* __restrict__ gw, const float* __restrict__ uw,
        const int* __restrict__ counts, const int* __restrict__ offs,
        const int* __restrict__ tok, float* __restrict__ t3) {
    const int e = blockIdx.z;
    const int cnt = counts[e];
    const int m0 = blockIdx.y << 6;
    if (m0 >= cnt) return;
    const int off = offs[e];
    const float* Bg = gw + (size_t)e * DD * FF;
    const float* Bu = uw + (size_t)e * DD * FF;
    __shared__ __align__(16) float As[16][68];
    __shared__ __align__(16) float Bgs[16][68];
    __shared__ __align__(16) float Bus[16][68];
    __shared__ int tks[64];
    const int tx = threadIdx.x, ty = threadIdx.y;
    const int tid = ty * 16 + tx;
    if (tid < 64) tks[tid] = (m0 + tid < cnt) ? tok[off + m0 + tid] : -1;
    __syncthreads();
    const int am = tid >> 2, ak = (tid & 3) << 2;
    const int bk = tid >> 4, bn = (tid & 15) << 2;
    const int col0 = blockIdx.x << 6;
    float ag[4][4] = {}, au[4][4] = {};
    for (int k0 = 0; k0 < DD; k0 += 16) {
        const int tk = tks[am];
        float4 av = make_float4(0.f, 0.f, 0.f, 0.f);
        if (tk >= 0) av = *(const float4*)(h + (size_t)tk * DD + (k0 + ak));
        As[ak + 0][am] = av.x; As[ak + 1][am] = av.y;
        As[ak + 2][am] = av.z; As[ak + 3][am] = av.w;
        *(float4*)&Bgs[bk][bn] = *(const float4*)(Bg + (size_t)(k0 + bk) * FF + col0 + bn);
        *(float4*)&Bus[bk][bn] = *(const float4*)(Bu + (size_t)(k0 + bk) * FF + col0 + bn);
        __syncthreads();
#pragma unroll
        for (int kk = 0; kk < 16; kk++) {
            const float4 a4 = *(const float4*)&As[kk][ty << 2];
            const float4 g4 = *(const float4*)&Bgs[kk][tx << 2];
            const float4 u4 = *(const float4*)&Bus[kk][tx << 2];
            const float ar[4] = {a4.x, a4.y, a4.z, a4.w};
            const float gr[4] = {g4.x, g4.y, g4.z, g4.w};
            const float ur[4] = {u4.x, u4.y, u4.z, u4.w};
#pragma unroll
            for (int i = 0; i < 4; i++)
#pragma unroll
                for (int j = 0; j < 4; j++) {
                    ag[i][j] = fmaf(ar[i], gr[j], ag[i][j]);
                    au[i][j] = fmaf(ar[i], ur[j], au[i][j]);
                }
        }
        __syncthreads();
    }
#pragma unroll
    for (int i = 0; i < 4; i++) {
        const int m = m0 + (ty << 2) + i;
        if (m >= cnt) continue;
        float* dst = t3 + (size_t)(off + m) * FF + col0 + (tx << 2);
        float4 v;
        v.x = ag[i][0] / (1.f + expf(-ag[i][0])) * au[i][0];
        v.y = ag[i][1] / (1.f + expf(-ag[i][1])) * au[i][1];
        v.z = ag[i][2] / (1.f + expf(-ag[i][2])) * au[i][2];
        v.w = ag[i][3] / (1.f + expf(-ag[i][3])) * au[i][3];
        *(float4*)dst = v;
    }
}

// grouped down-proj with gate-scaled atomic scatter-add into x
__global__ __launch_bounds__(256) void k_moe_down(const float* __restrict__ t3,
        const float* __restrict__ dw, const int* __restrict__ counts,
        const int* __restrict__ offs, const int* __restrict__ tok,
        const float* __restrict__ gv, float* __restrict__ x) {
    const int e = blockIdx.z;
    const int cnt = counts[e];
    const int m0 = blockIdx.y << 6;
    if (m0 >= cnt) return;
    const int off = offs[e];
    const float* B = dw + (size_t)e * FF * DD;
    __shared__ __align__(16) float As[16][68];
    __shared__ __align__(16) float Bs[16][68];
    __shared__ int tks[64];
    __shared__ float gvs[64];
    const int tx = threadIdx.x, ty = threadIdx.y;
    const int tid = ty * 16 + tx;
    if (tid < 64) {
        int ok = (m0 + tid < cnt);
        tks[tid] = ok ? tok[off + m0 + tid] : -1;
        gvs[tid] = ok ? gv[off + m0 + tid] : 0.f;
    }
    __syncthreads();
    const int am = tid >> 2, ak = (tid & 3) << 2;
    const int bk = tid >> 4, bn = (tid & 15) << 2;
    const int col0 = blockIdx.x << 6;
    float acc[4][4] = {};
    for (int k0 = 0; k0 < FF; k0 += 16) {
        float4 av = make_float4(0.f, 0.f, 0.f, 0.f);
        if (m0 + am < cnt)
            av = *(const float4*)(t3 + (size_t)(off + m0 + am) * FF + (k0 + ak));
        As[ak + 0][am] = av.x; As[ak + 1][am] = av.y;
        As[ak + 2][am] = av.z; As[ak + 3][am] = av.w;
        *(float4*)&Bs[bk][bn] = *(const float4*)(B + (size_t)(k0 + bk) * DD + col0 + bn);
        __syncthreads();
#pragma unroll
        for (int kk = 0; kk < 16; kk++) {
            const float4 a4 = *(const float4*)&As[kk][ty << 2];
            const float4 b4 = *(const float4*)&Bs[kk][tx << 2];
            const float ar[4] = {a4.x, a4.y, a4.z, a4.w};
            const float br[4] = {b4.x, b4.y, b4.z, b4.w};
#pragma unroll
            for (int i = 0; i < 4; i++)
#pragma unroll
                for (int j = 0; j < 4; j++)
                    acc[i][j] = fmaf(ar[i], br[j], acc[i][j]);
        }
        __syncthreads();
    }
#pragma unroll
    for (int i = 0; i < 4; i++) {
        const int r = (ty << 2) + i;
        const int m = m0 + r;
        if (m >= cnt) continue;
        const int tkn = tks[r];
        const float s = gvs[r];
        float* xp = x + (size_t)tkn * DD + col0 + (tx << 2);
#pragma unroll
        for (int j = 0; j < 4; j++) atomicAdd(&xp[j], s * acc[i][j]);
    }
}

// ---------------------------------------------------------------------------
extern "C" void kernel_launch(void* const* d_in, const int* in_sizes, int n_in,
                              void* d_out, int out_size, void* d_ws, size_t ws_size,
                              hipStream_t stream) {
    (void)in_sizes; (void)n_in; (void)out_size; (void)ws_size;
    const int*   token_ids    = (const int*)d_in[0];
    const int*   position_ids = (const int*)d_in[1];
    const float* tok_emb      = (const float*)d_in[2];
    const float* attn_norm_w  = (const float*)d_in[3];
    const float* wq           = (const float*)d_in[4];
    const float* wk           = (const float*)d_in[5];
    const float* wv           = (const float*)d_in[6];
    const float* q_norm_w     = (const float*)d_in[7];
    const float* k_norm_w     = (const float*)d_in[8];
    const float* wo           = (const float*)d_in[9];
    const float* ffn_norm_w   = (const float*)d_in[10];
    const float* router_w     = (const float*)d_in[11];
    const float* gate_w       = (const float*)d_in[12];
    const float* up_w         = (const float*)d_in[13];
    const float* down_w       = (const float*)d_in[14];
    const float* final_norm_w = (const float*)d_in[15];
    float* out = (float*)d_out;

    float* ws = (float*)d_ws;
    float* x      = ws;                                 // [TT, DD]
    float* h      = x   + (size_t)TT * DD;              // [TT, DD]
    float* qb     = h   + (size_t)TT * DD;              // [TT, HH*HDIM]
    float* kb     = qb  + (size_t)TT * DD;              // [TT, KVH*HDIM]
    float* vb     = kb  + (size_t)TT * KVH * HDIM;      // [TT, KVH*HDIM]
    float* ao     = vb  + (size_t)TT * KVH * HDIM;      // [TT, DD]
    float* rl     = ao  + (size_t)TT * DD;              // [TT, EE]
    float* t3     = rl  + (size_t)TT * EE;              // [NSLOT, FF]
    float* gv     = t3  + (size_t)NSLOT * FF;           // [NSLOT]
    float* tmp_gv = gv  + NSLOT;                        // [EE*TT]
    int*   tok     = (int*)(tmp_gv + (size_t)EE * TT);  // [NSLOT]
    int*   tmp_tok = tok + NSLOT;                       // [EE*TT]
    int*   counts  = tmp_tok + EE * TT;                 // [EE]
    int*   offs    = counts + EE;                       // [EE]

    dim3 blk2(16, 16);
    dim3 g_dd(DD / 64, TT / 64);          // 16 x 32
    dim3 g_qkv(DD / 64, TT / 64, 3);      // z: q / k / v
    dim3 g_r(1, TT / 64);                 // N=8 router logits
    dim3 g_lm(VV / 64, TT / 64);          // 500 x 32
    dim3 g_moe(FF / 64, TT / 64, EE);     // worst-case token blocks, early exit

    k_embed<<<TT, 256, 0, stream>>>(token_ids, tok_emb, x);

    for (int l = 0; l < LL; l++) {
        const float* wq_l = wq + (size_t)l * DD * (HH * HDIM);
        const float* wk_l = wk + (size_t)l * DD * (KVH * HDIM);
        const float* wv_l = wv + (size_t)l * DD * (KVH * HDIM);
        const float* wo_l = wo + (size_t)l * (HH * HDIM) * DD;
        const float* rw_l = router_w + (size_t)l * DD * EE;
        const float* gw_l = gate_w + (size_t)l * EE * DD * FF;
        const float* uw_l = up_w   + (size_t)l * EE * DD * FF;
        const float* dw_l = down_w + (size_t)l * EE * FF * DD;

        // ---- attention ----
        k_rmsnorm<<<TT, 256, 0, stream>>>(x, attn_norm_w + (size_t)l * DD, h);
        k_gemm_qkv<<<g_qkv, blk2, 0, stream>>>(h, wq_l, wk_l, wv_l, qb, kb, vb);
        k_qknorm_rope<<<(TT * HH) / 4, 256, 0, stream>>>(qb, q_norm_w + (size_t)l * HDIM,
                                                         position_ids, HH);
        k_qknorm_rope<<<(TT * KVH) / 4, 256, 0, stream>>>(kb, k_norm_w + (size_t)l * HDIM,
                                                          position_ids, KVH);
        k_attn<<<dim3(SS, BB * HH), 256, 0, stream>>>(qb, kb, vb, ao);
        k_gemm_nn<<<g_dd, blk2, 0, stream>>>(ao, wo_l, x, TT, DD, HH * HDIM, 1);

        // ---- MoE (sparse top-2) ----
        k_rmsnorm<<<TT, 256, 0, stream>>>(x, ffn_norm_w + (size_t)l * DD, h);
        k_gemm_nn<<<g_r, blk2, 0, stream>>>(h, rw_l, rl, TT, EE, DD, 0);
        k_zero_counts<<<1, 64, 0, stream>>>(counts);
        k_router_build<<<TT / 256, 256, 0, stream>>>(rl, counts, tmp_tok, tmp_gv);
        k_compact<<<1, 256, 0, stream>>>(counts, offs, tmp_tok, tmp_gv, tok, gv);
        k_moe_gateup<<<g_moe, blk2, 0, stream>>>(h, gw_l, uw_l, counts, offs, tok, t3);
        k_moe_down<<<g_moe, blk2, 0, stream>>>(t3, dw_l, counts, offs, tok, gv, x);
    }

    k_rmsnorm<<<TT, 256, 0, stream>>>(x, final_norm_w, h);
    k_gemm_nt<<<g_lm, blk2, 0, stream>>>(h, tok_emb, out, TT, VV, DD);
}

// Round 2
// 5810.207 us; speedup vs baseline: 6.1961x; 2.2202x over previous
//
#include <hip/hip_runtime.h>
#include <math.h>

// Problem constants (Qwen3-MoE tiny config)
#define BB    2
#define SS    1024
#define TT    2048          // B*S tokens
#define DD    1024          // model dim
#define HH    16            // q heads
#define KVH   4             // kv heads
#define HDIM  64            // head dim
#define LL    4             // layers
#define EE    8             // experts
#define FF    1024          // ffn dim
#define VV    32000         // vocab
#define EPSF  1e-6f
#define NSLOT 4096          // TT * TOPK slots

// ---------------------------------------------------------------------------
// embedding gather
__global__ void k_embed(const int* __restrict__ tok, const float* __restrict__ emb,
                        float* __restrict__ x) {
    int t = blockIdx.x;
    int id = tok[t];
    const float* src = emb + (size_t)id * DD;
    float* dst = x + (size_t)t * DD;
    for (int i = threadIdx.x; i < DD; i += blockDim.x) dst[i] = src[i];
}

// ---------------------------------------------------------------------------
// RMSNorm over D=1024, one block per row
__global__ void k_rmsnorm(const float* __restrict__ x, const float* __restrict__ w,
                          float* __restrict__ out) {
    int t = blockIdx.x;
    const float* row = x + (size_t)t * DD;
    float ss = 0.f;
    for (int i = threadIdx.x; i < DD; i += blockDim.x) { float v = row[i]; ss += v * v; }
    __shared__ float red[4];
    for (int o = 32; o > 0; o >>= 1) ss += __shfl_down(ss, o, 64);
    int lane = threadIdx.x & 63, wid = threadIdx.x >> 6;
    if (lane == 0) red[wid] = ss;
    __syncthreads();
    float tot = red[0] + red[1] + red[2] + red[3];
    float r = rsqrtf(tot / (float)DD + EPSF);
    float* o_ = out + (size_t)t * DD;
    for (int i = threadIdx.x; i < DD; i += blockDim.x) o_[i] = row[i] * r * w[i];
}

// ---------------------------------------------------------------------------
// 64x64 fp32 GEMM body. LDS stored [k][m] / [k][n] -> ds_read_b128 inner loop.
__device__ __forceinline__ void gemm64_body(const float* __restrict__ A,
        const float* __restrict__ B, float* __restrict__ C,
        int M, int N, int K, int accum) {
    __shared__ __align__(16) float As[16][68];
    __shared__ __align__(16) float Bs[16][68];
    const int tx = threadIdx.x, ty = threadIdx.y;
    const int tid = ty * 16 + tx;
    const int row0 = blockIdx.y << 6, col0 = blockIdx.x << 6;
    const int am = tid >> 2, ak = (tid & 3) << 2;    // A: 64 rows x 16 k
    const int bk = tid >> 4, bn = (tid & 15) << 2;   // B: 16 k x 64 cols
    float acc[4][4] = {};
    for (int k0 = 0; k0 < K; k0 += 16) {
        float4 av = make_float4(0.f, 0.f, 0.f, 0.f);
        const int gr = row0 + am;
        if (gr < M) av = *(const float4*)(A + (size_t)gr * K + (k0 + ak));
        As[ak + 0][am] = av.x; As[ak + 1][am] = av.y;
        As[ak + 2][am] = av.z; As[ak + 3][am] = av.w;
        float4 bv = make_float4(0.f, 0.f, 0.f, 0.f);
        const int gc = col0 + bn;
        const float* bp = B + (size_t)(k0 + bk) * N + gc;
        if (gc + 3 < N) bv = *(const float4*)bp;
        else if (gc < N) {
            bv.x = bp[0];
            if (gc + 1 < N) bv.y = bp[1];
            if (gc + 2 < N) bv.z = bp[2];
        }
        *(float4*)&Bs[bk][bn] = bv;
        __syncthreads();
#pragma unroll
        for (int kk = 0; kk < 16; kk++) {
            const float4 a4 = *(const float4*)&As[kk][ty << 2];
            const float4 b4 = *(const float4*)&Bs[kk][tx << 2];
            const float ar[4] = {a4.x, a4.y, a4.z, a4.w};
            const float br[4] = {b4.x, b4.y, b4.z, b4.w};
#pragma unroll
            for (int i = 0; i < 4; i++)
#pragma unroll
                for (int j = 0; j < 4; j++)
                    acc[i][j] = fmaf(ar[i], br[j], acc[i][j]);
        }
        __syncthreads();
    }
#pragma unroll
    for (int i = 0; i < 4; i++) {
        const int gr = row0 + (ty << 2) + i;
        if (gr >= M) continue;
        const int gc = col0 + (tx << 2);
        float* cp = C + (size_t)gr * N + gc;
        if (gc + 3 < N) {
            float4 v = make_float4(acc[i][0], acc[i][1], acc[i][2], acc[i][3]);
            if (accum) {
                const float4 o = *(const float4*)cp;
                v.x += o.x; v.y += o.y; v.z += o.z; v.w += o.w;
            }
            *(float4*)cp = v;
        } else {
#pragma unroll
            for (int j = 0; j < 4; j++)
                if (gc + j < N) {
                    float v = acc[i][j];
                    if (accum) v += cp[j];
                    cp[j] = v;
                }
        }
    }
}

__global__ __launch_bounds__(256) void k_gemm_nn(const float* __restrict__ A,
        const float* __restrict__ B, float* __restrict__ C, int M, int N, int K,
        int accum) {
    gemm64_body(A, B, C, M, N, K, accum);
}

// q/k/v fused into one launch: blockIdx.z selects {wq,wk,wv}
__global__ __launch_bounds__(256) void k_gemm_qkv(const float* __restrict__ h,
        const float* __restrict__ wq, const float* __restrict__ wk,
        const float* __restrict__ wv, float* __restrict__ qb,
        float* __restrict__ kb, float* __restrict__ vb) {
    const int z = blockIdx.z;
    const int N = (z == 0) ? (HH * HDIM) : (KVH * HDIM);
    if ((int)(blockIdx.x << 6) >= N) return;
    const float* B = (z == 0) ? wq : (z == 1 ? wk : wv);
    float* C = (z == 0) ? qb : (z == 1 ? kb : vb);
    gemm64_body(h, B, C, TT, N, DD, 0);
}

// ---------------------------------------------------------------------------
// GEMM-NT for the LM head: C[M,N] = A[M,K] @ B[N,K]^T (K contiguous in both)
__global__ __launch_bounds__(256) void k_gemm_nt(const float* __restrict__ A,
        const float* __restrict__ B, float* __restrict__ C, int M, int N, int K) {
    __shared__ __align__(16) float As[16][68];
    __shared__ __align__(16) float Bs[16][68];
    const int tx = threadIdx.x, ty = threadIdx.y;
    const int tid = ty * 16 + tx;
    const int row0 = blockIdx.y << 6, col0 = blockIdx.x << 6;
    const int am = tid >> 2, ak = (tid & 3) << 2;
    float acc[4][4] = {};
    for (int k0 = 0; k0 < K; k0 += 16) {
        float4 av = make_float4(0.f, 0.f, 0.f, 0.f);
        const int gr = row0 + am;
        if (gr < M) av = *(const float4*)(A + (size_t)gr * K + (k0 + ak));
        As[ak + 0][am] = av.x; As[ak + 1][am] = av.y;
        As[ak + 2][am] = av.z; As[ak + 3][am] = av.w;
        float4 bv = make_float4(0.f, 0.f, 0.f, 0.f);
        const int gn = col0 + am;
        if (gn < N) bv = *(const float4*)(B + (size_t)gn * K + (k0 + ak));
        Bs[ak + 0][am] = bv.x; Bs[ak + 1][am] = bv.y;
        Bs[ak + 2][am] = bv.z; Bs[ak + 3][am] = bv.w;
        __syncthreads();
#pragma unroll
        for (int kk = 0; kk < 16; kk++) {
            const float4 a4 = *(const float4*)&As[kk][ty << 2];
            const float4 b4 = *(const float4*)&Bs[kk][tx << 2];
            const float ar[4] = {a4.x, a4.y, a4.z, a4.w};
            const float br[4] = {b4.x, b4.y, b4.z, b4.w};
#pragma unroll
            for (int i = 0; i < 4; i++)
#pragma unroll
                for (int j = 0; j < 4; j++)
                    acc[i][j] = fmaf(ar[i], br[j], acc[i][j]);
        }
        __syncthreads();
    }
#pragma unroll
    for (int i = 0; i < 4; i++) {
        const int gr = row0 + (ty << 2) + i;
        if (gr >= M) continue;
        const int gc = col0 + (tx << 2);
        float* cp = C + (size_t)gr * N + gc;
        if (gc + 3 < N) {
            *(float4*)cp = make_float4(acc[i][0], acc[i][1], acc[i][2], acc[i][3]);
        } else {
#pragma unroll
            for (int j = 0; j < 4; j++)
                if (gc + j < N) cp[j] = acc[i][j];
        }
    }
}

// ---------------------------------------------------------------------------
// per-head RMSNorm (over 64 dims) + RoPE. One 64-lane wave per (token, head).
__global__ void k_qknorm_rope(float* __restrict__ q, const float* __restrict__ nw,
                              const int* __restrict__ pos_ids, int nheads) {
    int g = blockIdx.x * 4 + (threadIdx.x >> 6);
    int lane = threadIdx.x & 63;
    int t = g / nheads, head = g % nheads;
    size_t base = (size_t)t * nheads * HDIM + (size_t)head * HDIM;
    float v = q[base + lane];
    float ss = v * v;
    for (int o = 32; o > 0; o >>= 1) ss += __shfl_xor(ss, o, 64);
    float r = rsqrtf(ss / (float)HDIM + EPSF);
    v = v * r * nw[lane];
    int pos = pos_ids[t];
    int i = lane & 31;
    float freq = powf(1000000.0f, -(float)i / 32.0f);
    float ang = (float)pos * freq;
    float c = cosf(ang), s = sinf(ang);
    float partner = __shfl_xor(v, 32, 64);
    float outv = (lane < 32) ? (v * c - partner * s) : (v * c + partner * s);
    q[base + lane] = outv;
}

// ---------------------------------------------------------------------------
// Tiled flash attention: one block = 64 queries x 1 head; loop over 64-wide
// K/V tiles with online softmax. QK and PV passes use the [k][row]-major LDS
// + ds_read_b128 + 4x4 register-tile pattern (same engine as gemm64_body).
__global__ __launch_bounds__(256) void k_attn_flash(const float* __restrict__ q,
        const float* __restrict__ k, const float* __restrict__ v,
        float* __restrict__ o) {
    const int qt = (gridDim.x - 1) - blockIdx.x;   // heavy tiles first
    const int bh = blockIdx.y;
    const int b = bh / HH, h = bh % HH;
    const int kvh = h >> 2;                        // GQA: 4 q heads per kv head
    const int q0 = qt << 6;
    __shared__ __align__(16) float Qs[64][68];     // [d][i]
    __shared__ __align__(16) float Ks[64][68];     // [d][j]
    __shared__ __align__(16) float Vs[64][68];     // [j][d]
    __shared__ __align__(16) float Ps[64][68];     // [j][i]
    const int tx = threadIdx.x, ty = threadIdx.y;
    const int tid = ty * 16 + tx;
    // load Q tile transposed into [d][i]
    {
        const float* qb_ = q + ((size_t)(b * SS + q0) * HH + h) * HDIM;
#pragma unroll
        for (int c = 0; c < 4; c++) {
            int idx = tid + c * 256;
            int row = idx >> 4, d0 = (idx & 15) << 2;
            float4 qv = *(const float4*)(qb_ + (size_t)row * (HH * HDIM) + d0);
            Qs[d0 + 0][row] = qv.x; Qs[d0 + 1][row] = qv.y;
            Qs[d0 + 2][row] = qv.z; Qs[d0 + 3][row] = qv.w;
        }
    }
    float oacc[4][4] = {};
    float m[4] = {-1e30f, -1e30f, -1e30f, -1e30f};
    float l[4] = {};
    const float scale = 0.125f;                    // 1/sqrt(64)
    for (int jt = 0; jt <= qt; jt++) {
        const int j0 = jt << 6;
        // load K (transposed) and V tiles
        const float* kb_ = k + ((size_t)(b * SS + j0) * KVH + kvh) * HDIM;
        const float* vb_ = v + ((size_t)(b * SS + j0) * KVH + kvh) * HDIM;
#pragma unroll
        for (int c = 0; c < 4; c++) {
            int idx = tid + c * 256;
            int row = idx >> 4, d0 = (idx & 15) << 2;
            float4 kv = *(const float4*)(kb_ + (size_t)row * (KVH * HDIM) + d0);
            Ks[d0 + 0][row] = kv.x; Ks[d0 + 1][row] = kv.y;
            Ks[d0 + 2][row] = kv.z; Ks[d0 + 3][row] = kv.w;
            *(float4*)&Vs[row][d0] = *(const float4*)(vb_ + (size_t)row * (KVH * HDIM) + d0);
        }
        __syncthreads();
        // scores: s4[i][j] over rows q0+ty*4+i, cols j0+tx*4+j
        float s4[4][4] = {};
#pragma unroll 8
        for (int d = 0; d < 64; d++) {
            const float4 qa = *(const float4*)&Qs[d][ty << 2];
            const float4 ka = *(const float4*)&Ks[d][tx << 2];
            const float ar[4] = {qa.x, qa.y, qa.z, qa.w};
            const float br[4] = {ka.x, ka.y, ka.z, ka.w};
#pragma unroll
            for (int i = 0; i < 4; i++)
#pragma unroll
                for (int j = 0; j < 4; j++)
                    s4[i][j] = fmaf(ar[i], br[j], s4[i][j]);
        }
#pragma unroll
        for (int i = 0; i < 4; i++)
#pragma unroll
            for (int j = 0; j < 4; j++) s4[i][j] *= scale;
        if (jt == qt) {   // causal mask on the diagonal tile
#pragma unroll
            for (int i = 0; i < 4; i++)
#pragma unroll
                for (int j = 0; j < 4; j++)
                    if (((tx << 2) + j) > ((ty << 2) + i)) s4[i][j] = -1e30f;
        }
        // per-row tile max (reduce across the 16 threads sharing ty)
        float tm[4], ts[4], f[4];
#pragma unroll
        for (int i = 0; i < 4; i++)
            tm[i] = fmaxf(fmaxf(s4[i][0], s4[i][1]), fmaxf(s4[i][2], s4[i][3]));
#pragma unroll
        for (int msk = 1; msk < 16; msk <<= 1)
#pragma unroll
            for (int i = 0; i < 4; i++) tm[i] = fmaxf(tm[i], __shfl_xor(tm[i], msk, 64));
#pragma unroll
        for (int i = 0; i < 4; i++) {
            float mn = fmaxf(m[i], tm[i]);
            f[i] = expf(m[i] - mn);
            m[i] = mn;
        }
        float p4[4][4];
#pragma unroll
        for (int i = 0; i < 4; i++) {
#pragma unroll
            for (int j = 0; j < 4; j++) p4[i][j] = expf(s4[i][j] - m[i]);
            ts[i] = (p4[i][0] + p4[i][1]) + (p4[i][2] + p4[i][3]);
        }
#pragma unroll
        for (int msk = 1; msk < 16; msk <<= 1)
#pragma unroll
            for (int i = 0; i < 4; i++) ts[i] += __shfl_xor(ts[i], msk, 64);
#pragma unroll
        for (int i = 0; i < 4; i++) {
            l[i] = l[i] * f[i] + ts[i];
#pragma unroll
            for (int d = 0; d < 4; d++) oacc[i][d] *= f[i];
        }
        // write P transposed [j][i]
#pragma unroll
        for (int i = 0; i < 4; i++)
#pragma unroll
            for (int j = 0; j < 4; j++)
                Ps[(tx << 2) + j][(ty << 2) + i] = p4[i][j];
        __syncthreads();
        // PV: oacc[i][d] += P[i][j] * V[j][d]
#pragma unroll 8
        for (int j = 0; j < 64; j++) {
            const float4 pa = *(const float4*)&Ps[j][ty << 2];
            const float4 va = *(const float4*)&Vs[j][tx << 2];
            const float pr[4] = {pa.x, pa.y, pa.z, pa.w};
            const float vr[4] = {va.x, va.y, va.z, va.w};
#pragma unroll
            for (int i = 0; i < 4; i++)
#pragma unroll
                for (int d = 0; d < 4; d++)
                    oacc[i][d] = fmaf(pr[i], vr[d], oacc[i][d]);
        }
        __syncthreads();
    }
    // epilogue: normalize and store
#pragma unroll
    for (int i = 0; i < 4; i++) {
        const float inv = 1.f / l[i];
        const int t = b * SS + q0 + (ty << 2) + i;
        float4 ov = make_float4(oacc[i][0] * inv, oacc[i][1] * inv,
                                oacc[i][2] * inv, oacc[i][3] * inv);
        *(float4*)(o + ((size_t)t * HH + h) * HDIM + (tx << 2)) = ov;
    }
}

// ---------------------------------------------------------------------------
// MoE routing: fused logits (wave per token) + top-2 of 8 + bucketing
__global__ void k_zero_counts(int* __restrict__ counts) {
    if (threadIdx.x < EE) counts[threadIdx.x] = 0;
}

__global__ void k_router_fused(const float* __restrict__ h, const float* __restrict__ rw,
                               int* __restrict__ counts, int* __restrict__ tmp_tok,
                               float* __restrict__ tmp_gv) {
    const int wid = threadIdx.x >> 6, lane = threadIdx.x & 63;
    const int t = blockIdx.x * 4 + wid;
    const float* hr = h + (size_t)t * DD;
    float lg[EE] = {};
#pragma unroll
    for (int kk = 0; kk < DD / 64; kk++) {
        const int d = kk * 64 + lane;
        const float hv = hr[d];
        const float4 r0 = *(const float4*)(rw + (size_t)d * EE);
        const float4 r1 = *(const float4*)(rw + (size_t)d * EE + 4);
        lg[0] = fmaf(hv, r0.x, lg[0]); lg[1] = fmaf(hv, r0.y, lg[1]);
        lg[2] = fmaf(hv, r0.z, lg[2]); lg[3] = fmaf(hv, r0.w, lg[3]);
        lg[4] = fmaf(hv, r1.x, lg[4]); lg[5] = fmaf(hv, r1.y, lg[5]);
        lg[6] = fmaf(hv, r1.z, lg[6]); lg[7] = fmaf(hv, r1.w, lg[7]);
    }
#pragma unroll
    for (int o = 32; o > 0; o >>= 1)
#pragma unroll
        for (int e = 0; e < EE; e++) lg[e] += __shfl_xor(lg[e], o, 64);
    if (lane == 0) {
        int i0 = 0; float l0 = lg[0];
        for (int e = 1; e < EE; e++) if (lg[e] > l0) { l0 = lg[e]; i0 = e; }
        int i1 = -1; float l1 = -1e30f;
        for (int e = 0; e < EE; e++) {
            if (e == i0) continue;
            if (i1 < 0 || lg[e] > l1) { l1 = lg[e]; i1 = e; }
        }
        const float d = expf(l1 - l0);
        const float w0 = 1.f / (1.f + d), w1 = d / (1.f + d);
        int p = atomicAdd(&counts[i0], 1);
        tmp_tok[i0 * TT + p] = t; tmp_gv[i0 * TT + p] = w0;
        p = atomicAdd(&counts[i1], 1);
        tmp_tok[i1 * TT + p] = t; tmp_gv[i1 * TT + p] = w1;
    }
}

// compact per-expert lists into contiguous slot space
__global__ void k_compact(const int* __restrict__ counts, int* __restrict__ offs,
                          const int* __restrict__ tmp_tok, const float* __restrict__ tmp_gv,
                          int* __restrict__ tok, float* __restrict__ gv) {
    __shared__ int so[EE];
    int tid = threadIdx.x;
    if (tid == 0) {
        int r = 0;
        for (int e = 0; e < EE; e++) { so[e] = r; offs[e] = r; r += counts[e]; }
    }
    __syncthreads();
    for (int e = 0; e < EE; e++) {
        int c = counts[e], o = so[e];
        for (int i = tid; i < c; i += 256) {
            tok[o + i] = tmp_tok[e * TT + i];
            gv[o + i]  = tmp_gv[e * TT + i];
        }
    }
}

// ---------------------------------------------------------------------------
// grouped gather gate+up GEMM with fused silu
__global__ __launch_bounds__(256) void k_moe_gateup(const float* __restrict__ h,
        const float* __restrict__ gw, const float* __restrict__ uw,
        const int* __restrict__ counts, const int* __restrict__ offs,
        const int* __restrict__ tok, float* __restrict__ t3) {
    const int e = blockIdx.z;
    const int cnt = counts[e];
    const int m0 = blockIdx.y << 6;
    if (m0 >= cnt) return;
    const int off = offs[e];
    const float* Bg = gw + (size_t)e * DD * FF;
    const float* Bu = uw + (size_t)e * DD * FF;
    __shared__ __align__(16) float As[16][68];
    __shared__ __align__(16) float Bgs[16][68];
    __shared__ __align__(16) float Bus[16][68];
    __shared__ int tks[64];
    const int tx = threadIdx.x, ty = threadIdx.y;
    const int tid = ty * 16 + tx;
    if (tid < 64) tks[tid] = (m0 + tid < cnt) ? tok[off + m0 + tid] : -1;
    __syncthreads();
    const int am = tid >> 2, ak = (tid & 3) << 2;
    const int bk = tid >> 4, bn = (tid & 15) << 2;
    const int col0 = blockIdx.x << 6;
    float ag[4][4] = {}, au[4][4] = {};
    for (int k0 = 0; k0 < DD; k0 += 16) {
        const int tk = tks[am];
        float4 av = make_float4(0.f, 0.f, 0.f, 0.f);
        if (tk >= 0) av = *(const float4*)(h + (size_t)tk * DD + (k0 + ak));
        As[ak + 0][am] = av.x; As[ak + 1][am] = av.y;
        As[ak + 2][am] = av.z; As[ak + 3][am] = av.w;
        *(float4*)&Bgs[bk][bn] = *(const float4*)(Bg + (size_t)(k0 + bk) * FF + col0 + bn);
        *(float4*)&Bus[bk][bn] = *(const float4*)(Bu + (size_t)(k0 + bk) * FF + col0 + bn);
        __syncthreads();
#pragma unroll
        for (int kk = 0; kk < 16; kk++) {
            const float4 a4 = *(const float4*)&As[kk][ty << 2];
            const float4 g4 = *(const float4*)&Bgs[kk][tx << 2];
            const float4 u4 = *(const float4*)&Bus[kk][tx << 2];
            const float ar[4] = {a4.x, a4.y, a4.z, a4.w};
            const float gr[4] = {g4.x, g4.y, g4.z, g4.w};
            const float ur[4] = {u4.x, u4.y, u4.z, u4.w};
#pragma unroll
            for (int i = 0; i < 4; i++)
#pragma unroll
                for (int j = 0; j < 4; j++) {
                    ag[i][j] = fmaf(ar[i], gr[j], ag[i][j]);
                    au[i][j] = fmaf(ar[i], ur[j], au[i][j]);
                }
        }
        __syncthreads();
    }
#pragma unroll
    for (int i = 0; i < 4; i++) {
        const int m = m0 + (ty << 2) + i;
        if (m >= cnt) continue;
        float* dst = t3 + (size_t)(off + m) * FF + col0 + (tx << 2);
        float4 v;
        v.x = ag[i][0] / (1.f + expf(-ag[i][0])) * au[i][0];
        v.y = ag[i][1] / (1.f + expf(-ag[i][1])) * au[i][1];
        v.z = ag[i][2] / (1.f + expf(-ag[i][2])) * au[i][2];
        v.w = ag[i][3] / (1.f + expf(-ag[i][3])) * au[i][3];
        *(float4*)dst = v;
    }
}

// grouped down-proj with gate-scaled atomic scatter-add into x
__global__ __launch_bounds__(256) void k_moe_down(const float* __restrict__ t3,
        const float* __restrict__ dw, const int* __restrict__ counts,
        const int* __restrict__ offs, const int* __restrict__ tok,
        const float* __restrict__ gv, float* __restrict__ x) {
    const int e = blockIdx.z;
    const int cnt = counts[e];
    const int m0 = blockIdx.y << 6;
    if (m0 >= cnt) return;
    const int off = offs[e];
    const float* B = dw + (size_t)e * FF * DD;
    __shared__ __align__(16) float As[16][68];
    __shared__ __align__(16) float Bs[16][68];
    __shared__ int tks[64];
    __shared__ float gvs[64];
    const int tx = threadIdx.x, ty = threadIdx.y;
    const int tid = ty * 16 + tx;
    if (tid < 64) {
        int ok = (m0 + tid < cnt);
        tks[tid] = ok ? tok[off + m0 + tid] : -1;
        gvs[tid] = ok ? gv[off + m0 + tid] : 0.f;
    }
    __syncthreads();
    const int am = tid >> 2, ak = (tid & 3) << 2;
    const int bk = tid >> 4, bn = (tid & 15) << 2;
    const int col0 = blockIdx.x << 6;
    float acc[4][4] = {};
    for (int k0 = 0; k0 < FF; k0 += 16) {
        float4 av = make_float4(0.f, 0.f, 0.f, 0.f);
        if (m0 + am < cnt)
            av = *(const float4*)(t3 + (size_t)(off + m0 + am) * FF + (k0 + ak));
        As[ak + 0][am] = av.x; As[ak + 1][am] = av.y;
        As[ak + 2][am] = av.z; As[ak + 3][am] = av.w;
        *(float4*)&Bs[bk][bn] = *(const float4*)(B + (size_t)(k0 + bk) * DD + col0 + bn);
        __syncthreads();
#pragma unroll
        for (int kk = 0; kk < 16; kk++) {
            const float4 a4 = *(const float4*)&As[kk][ty << 2];
            const float4 b4 = *(const float4*)&Bs[kk][tx << 2];
            const float ar[4] = {a4.x, a4.y, a4.z, a4.w};
            const float br[4] = {b4.x, b4.y, b4.z, b4.w};
#pragma unroll
            for (int i = 0; i < 4; i++)
#pragma unroll
                for (int j = 0; j < 4; j++)
                    acc[i][j] = fmaf(ar[i], br[j], acc[i][j]);
        }
        __syncthreads();
    }
#pragma unroll
    for (int i = 0; i < 4; i++) {
        const int r = (ty << 2) + i;
        const int m = m0 + r;
        if (m >= cnt) continue;
        const int tkn = tks[r];
        const float s = gvs[r];
        float* xp = x + (size_t)tkn * DD + col0 + (tx << 2);
#pragma unroll
        for (int j = 0; j < 4; j++) atomicAdd(&xp[j], s * acc[i][j]);
    }
}

// ---------------------------------------------------------------------------
extern "C" void kernel_launch(void* const* d_in, const int* in_sizes, int n_in,
                              void* d_out, int out_size, void* d_ws, size_t ws_size,
                              hipStream_t stream) {
    (void)in_sizes; (void)n_in; (void)out_size; (void)ws_size;
    const int*   token_ids    = (const int*)d_in[0];
    const int*   position_ids = (const int*)d_in[1];
    const float* tok_emb      = (const float*)d_in[2];
    const float* attn_norm_w  = (const float*)d_in[3];
    const float* wq           = (const float*)d_in[4];
    const float* wk           = (const float*)d_in[5];
    const float* wv           = (const float*)d_in[6];
    const float* q_norm_w     = (const float*)d_in[7];
    const float* k_norm_w     = (const float*)d_in[8];
    const float* wo           = (const float*)d_in[9];
    const float* ffn_norm_w   = (const float*)d_in[10];
    const float* router_w     = (const float*)d_in[11];
    const float* gate_w       = (const float*)d_in[12];
    const float* up_w         = (const float*)d_in[13];
    const float* down_w       = (const float*)d_in[14];
    const float* final_norm_w = (const float*)d_in[15];
    float* out = (float*)d_out;

    float* ws = (float*)d_ws;
    float* x      = ws;                                 // [TT, DD]
    float* h      = x   + (size_t)TT * DD;              // [TT, DD]
    float* qb     = h   + (size_t)TT * DD;              // [TT, HH*HDIM]
    float* kb     = qb  + (size_t)TT * DD;              // [TT, KVH*HDIM]
    float* vb     = kb  + (size_t)TT * KVH * HDIM;      // [TT, KVH*HDIM]
    float* ao     = vb  + (size_t)TT * KVH * HDIM;      // [TT, DD]
    float* rl     = ao  + (size_t)TT * DD;              // [TT, EE] (unused now)
    float* t3     = rl  + (size_t)TT * EE;              // [NSLOT, FF]
    float* gv     = t3  + (size_t)NSLOT * FF;           // [NSLOT]
    float* tmp_gv = gv  + NSLOT;                        // [EE*TT]
    int*   tok     = (int*)(tmp_gv + (size_t)EE * TT);  // [NSLOT]
    int*   tmp_tok = tok + NSLOT;                       // [EE*TT]
    int*   counts  = tmp_tok + EE * TT;                 // [EE]
    int*   offs    = counts + EE;                       // [EE]

    dim3 blk2(16, 16);
    dim3 g_dd(DD / 64, TT / 64);          // 16 x 32
    dim3 g_qkv(DD / 64, TT / 64, 3);      // z: q / k / v
    dim3 g_lm(VV / 64, TT / 64);          // 500 x 32
    dim3 g_moe(FF / 64, TT / 64, EE);     // worst-case token blocks, early exit
    dim3 g_at(SS / 64, BB * HH);          // 16 x 32 flash tiles

    k_embed<<<TT, 256, 0, stream>>>(token_ids, tok_emb, x);

    for (int l = 0; l < LL; l++) {
        const float* wq_l = wq + (size_t)l * DD * (HH * HDIM);
        const float* wk_l = wk + (size_t)l * DD * (KVH * HDIM);
        const float* wv_l = wv + (size_t)l * DD * (KVH * HDIM);
        const float* wo_l = wo + (size_t)l * (HH * HDIM) * DD;
        const float* rw_l = router_w + (size_t)l * DD * EE;
        const float* gw_l = gate_w + (size_t)l * EE * DD * FF;
        const float* uw_l = up_w   + (size_t)l * EE * DD * FF;
        const float* dw_l = down_w + (size_t)l * EE * FF * DD;

        // ---- attention ----
        k_rmsnorm<<<TT, 256, 0, stream>>>(x, attn_norm_w + (size_t)l * DD, h);
        k_gemm_qkv<<<g_qkv, blk2, 0, stream>>>(h, wq_l, wk_l, wv_l, qb, kb, vb);
        k_qknorm_rope<<<(TT * HH) / 4, 256, 0, stream>>>(qb, q_norm_w + (size_t)l * HDIM,
                                                         position_ids, HH);
        k_qknorm_rope<<<(TT * KVH) / 4, 256, 0, stream>>>(kb, k_norm_w + (size_t)l * HDIM,
                                                          position_ids, KVH);
        k_attn_flash<<<g_at, blk2, 0, stream>>>(qb, kb, vb, ao);
        k_gemm_nn<<<g_dd, blk2, 0, stream>>>(ao, wo_l, x, TT, DD, HH * HDIM, 1);

        // ---- MoE (sparse top-2) ----
        k_rmsnorm<<<TT, 256, 0, stream>>>(x, ffn_norm_w + (size_t)l * DD, h);
        k_zero_counts<<<1, 64, 0, stream>>>(counts);
        k_router_fused<<<TT / 4, 256, 0, stream>>>(h, rw_l, counts, tmp_tok, tmp_gv);
        k_compact<<<1, 256, 0, stream>>>(counts, offs, tmp_tok, tmp_gv, tok, gv);
        k_moe_gateup<<<g_moe, blk2, 0, stream>>>(h, gw_l, uw_l, counts, offs, tok, t3);
        k_moe_down<<<g_moe, blk2, 0, stream>>>(t3, dw_l, counts, offs, tok, gv, x);
    }

    k_rmsnorm<<<TT, 256, 0, stream>>>(x, final_norm_w, h);
    k_gemm_nt<<<g_lm, blk2, 0, stream>>>(h, tok_emb, out, TT, VV, DD);
}